// Round 20
// baseline (290.599 us; speedup 1.0000x reference)
//
#include <hip/hip_runtime.h>

#define NROWS 8192
#define BBND  32
#define CBND  512
#define JQ    4096            // j-range per block (2 halves)
#define NR    64              // rounds of 64j per block
#define ABUFB 8192            // A LDS buffer bytes (64 rows x 128B)

typedef unsigned short u16;
typedef unsigned int   u32;
typedef __bf16 bf16x8 __attribute__((ext_vector_type(8)));
typedef float  f32x4  __attribute__((ext_vector_type(4)));
typedef float  f32x16 __attribute__((ext_vector_type(16)));
typedef u32    u32x4  __attribute__((ext_vector_type(4)));
typedef u32    u32x2  __attribute__((ext_vector_type(2)));

#define ZERO4  (f32x4){0.f,0.f,0.f,0.f}
#define ZERO16 (f32x16){0.f,0.f,0.f,0.f,0.f,0.f,0.f,0.f,0.f,0.f,0.f,0.f,0.f,0.f,0.f,0.f}

// raw barrier: drain LDS ops, keep global loads in flight (no vmcnt drain)
#define BAR asm volatile("s_waitcnt lgkmcnt(0)\n\ts_barrier" ::: "memory")

static __device__ inline u16 f2bf(float f) {
    unsigned u = __builtin_bit_cast(unsigned, f);
    unsigned r = (u + 0x7FFFu + ((u >> 16) & 1u)) >> 16;
    return (u16)r;
}

static __device__ inline float pow14(float base) {
    return __builtin_amdgcn_exp2f(1.4f * __builtin_amdgcn_logf(base));
}

static __device__ inline float adj_eval(float dot, float sij) {
    float x = fabsf(2.f * dot - sij);
    float base = fmaxf(1.f - x * (1.f / 32.f), 0.f);
    return pow14(base);
}

static __device__ inline float sigmoidf_fast(float v) {
    float e = __builtin_amdgcn_exp2f(-1.44269504f * v);
    return 1.f / (1.f + e);
}

static __device__ inline u32 cvtpk(float a, float b) {
    u32 r;
    asm("v_cvt_pk_bf16_f32 %0, %1, %2" : "=v"(r) : "v"(a), "v"(b));
    return r;
}

static __device__ inline f32x4 MFMA16(bf16x8 a, bf16x8 b, f32x4 c) {
    return __builtin_amdgcn_mfma_f32_16x16x32_bf16(a, b, c, 0, 0, 0);
}
static __device__ inline f32x16 MFMA32(bf16x8 a, bf16x8 b, f32x16 c) {
    return __builtin_amdgcn_mfma_f32_32x32x16_bf16(a, b, c, 0, 0, 0);
}

// ---------------- prep: WT transpose + row sums/bf16 + zero split-K flags ----------------
__global__ __launch_bounds__(512) void k_prep(const float* __restrict__ bbn,
                                              const float* __restrict__ W,
                                              float* __restrict__ s,
                                              u16* __restrict__ bbn_bf,
                                              u16* __restrict__ WT,
                                              int* __restrict__ flags) {
    int idx = blockIdx.x * 512 + threadIdx.x;   // 512 blocks x 512 thr = 262144
    int c = idx >> 9, k = idx & 511;
    WT[idx] = f2bf(W[k * CBND + c]);            // WT[c][k]
    if (idx < 128) flags[idx] = 0;
    if (idx < NROWS) {
        const f32x4* row = reinterpret_cast<const f32x4*>(bbn + idx * BBND);
        float sum = 0.f;
        u16* dst = bbn_bf + idx * BBND;
#pragma unroll
        for (int q = 0; q < 8; ++q) {
            f32x4 v = row[q];
#pragma unroll
            for (int e = 0; e < 4; ++e) {
                sum += v[e];
                dst[q * 4 + e] = f2bf(v[e]);
            }
        }
        s[idx] = sum;
    }
}

// ---------------- degree: d_i = sum_j adj_ij ; dinv = rsqrt(d+eps) (r18 verbatim) ----------------
__global__ __launch_bounds__(1024) void k_deg(const u16* __restrict__ bbn_bf,
                                              const float* __restrict__ s,
                                              float* __restrict__ dinv) {
    __shared__ float part[16][16];
    int ibase = blockIdx.x * 16;
    int tid = threadIdx.x;
    int w = tid >> 6, l = tid & 63, lg = l >> 4, lr = l & 15;

    bf16x8 afrag = *reinterpret_cast<const bf16x8*>(bbn_bf + (ibase + lr) * BBND + lg * 8);
    float si[4];
#pragma unroll
    for (int r = 0; r < 4; ++r) si[r] = s[ibase + lg * 4 + r];

    float dacc[4] = {0.f, 0.f, 0.f, 0.f};
    int j0 = w * (NROWS / 16);
    bf16x8 nbf = *reinterpret_cast<const bf16x8*>(bbn_bf + (j0 + lr) * BBND + lg * 8);
    float nsj = s[j0 + lr];
    for (int jt = 0; jt < NROWS / 16; jt += 16) {
        bf16x8 bfrag = nbf;
        float sj = nsj;
        if (jt + 16 < NROWS / 16) {
            int jn = j0 + jt + 16;
            nbf = *reinterpret_cast<const bf16x8*>(bbn_bf + (jn + lr) * BBND + lg * 8);
            nsj = s[jn + lr];
        }
        f32x4 dot = MFMA16(afrag, bfrag, ZERO4);
#pragma unroll
        for (int r = 0; r < 4; ++r) dacc[r] += adj_eval(dot[r], si[r] + sj);
    }
#pragma unroll
    for (int off = 1; off < 16; off <<= 1)
#pragma unroll
        for (int r = 0; r < 4; ++r) dacc[r] += __shfl_xor(dacc[r], off, 64);

    if (lr == 0) {
#pragma unroll
        for (int r = 0; r < 4; ++r) part[w][lg * 4 + r] = dacc[r];
    }
    __syncthreads();
    if (tid < 16) {
        float d = 0.f;
#pragma unroll
        for (int q = 0; q < 16; ++q) d += part[q][tid];
        dinv[ibase + tid] = rsqrtf(d + 1e-8f);
    }
}

// ---------------- fc: g_blk[(j>>3)*512 + c][j&7] = dinv_j * (cbn@W + b)[j][c] (r18 verbatim) ----------------
__global__ __launch_bounds__(512) void k_fc(const float* __restrict__ cbn,
                                            const u16* __restrict__ WT,
                                            const float* __restrict__ bvec,
                                            const float* __restrict__ dinv,
                                            u16* __restrict__ g_blk) {
    __shared__ __align__(16) u16 Clds[64 * 512];   // 64 j-rows x 512 k (bf16)
    int bx = blockIdx.x;
    int ch = bx & 1;
    int jcol = (bx >> 1) * 64;
    int tid = threadIdx.x;
    int w = tid >> 6, l = tid & 63, lg = l >> 4, lr = l & 15;
    int wq = w & 3, jh = w >> 2;

    char* Cl = (char*)&Clds[0];

#pragma unroll
    for (int p = 0; p < 8; ++p) {
        int gidx = p * 512 + tid;
        int row = gidx >> 6, sl = gidx & 63;
        const f32x4* src = reinterpret_cast<const f32x4*>(cbn + (jcol + row) * CBND + sl * 8);
        f32x4 v0 = src[0], v1 = src[1];
        bf16x8 bv;
#pragma unroll
        for (int e = 0; e < 4; ++e) { bv[e] = (__bf16)v0[e]; bv[e + 4] = (__bf16)v1[e]; }
        *reinterpret_cast<bf16x8*>(Cl + row * 1024 + ((sl ^ (row & 7)) << 4)) = bv;
    }
    __syncthreads();

    int r7 = lr & 7;
    for (int q = 0; q < 4; ++q) {
        int cb = ch * 4 + q;
        int crow = cb * 64 + wq * 16;
        f32x4 acc0 = ZERO4, acc1 = ZERO4;
        for (int k0 = 0; k0 < CBND; k0 += 32) {
            bf16x8 afrag = *reinterpret_cast<const bf16x8*>(WT + (crow + lr) * CBND + k0 + lg * 8);
            int slot = (k0 >> 3) + lg;
            int row0 = jh * 32 + lr;
            bf16x8 b0 = *reinterpret_cast<const bf16x8*>(Cl + row0 * 1024 + ((slot ^ r7) << 4));
            bf16x8 b1 = *reinterpret_cast<const bf16x8*>(Cl + (row0 + 16) * 1024 + ((slot ^ r7) << 4));
            acc0 = MFMA16(afrag, b0, acc0);
            acc1 = MFMA16(afrag, b1, acc1);
        }
#pragma unroll
        for (int f = 0; f < 2; ++f) {
            f32x4 af = f ? acc1 : acc0;
#pragma unroll
            for (int r = 0; r < 4; ++r) {
                int c = crow + lg * 4 + r;
                int j = jcol + jh * 32 + f * 16 + lr;
                float val = af[r] + bvec[c];
                g_blk[(((j >> 3) * 512 + c) << 3) + (j & 7)] = f2bf(val * dinv[j]);
            }
        }
    }
}

// ---------------- conv: partials + fused split-K combine ----------------
// r18-verbatim conv core (86.7us proven). After EPI, split-K flag pattern:
// each of the 2 j-half blocks per i-tile bumps flags[it] (device-scope atomic,
// fenced); the SECOND finisher reads both partials (fixed order P0+P1 -> values
// identical to the old k_comb) and writes sigmoid(dinv_i*(P0+P1)) to out.
// 128 atomics total; no spinning (first finisher just exits) -> no deadlock,
// deterministic output.

#define LOADB(T, R) { \
    const char* p = gB + (long)(T) * 65536; \
    R##0 = *reinterpret_cast<const u32x4*>(p); \
    R##1 = *reinterpret_cast<const u32x4*>(p + 16384); \
    R##2 = *reinterpret_cast<const u32x4*>(p + 32768); \
    R##3 = *reinterpret_cast<const u32x4*>(p + 49152); \
}

#define LOADG(ST) { \
    int jg = jbase + (ST) * 64 + jq8 * 16; \
    gJ = *reinterpret_cast<const bf16x8*>(bbn_bf + (jg + lr) * BBND + lg * 8); \
    gS = *reinterpret_cast<const f32x4*>(s + jg + lg * 4); \
}

#define GENP(WB) { \
    f32x4 dot = MFMA16(gJ, fragI, ZERO4); \
    u32 p0 = cvtpk(adj_eval(dot[0], si + gS[0]), adj_eval(dot[1], si + gS[1])); \
    u32 p1 = cvtpk(adj_eval(dot[2], si + gS[2]), adj_eval(dot[3], si + gS[3])); \
    *reinterpret_cast<u32x2*>(Ab + (WB) * ABUFB + gw) = (u32x2){p0, p1}; \
}

#define CONVP(RB, R) { \
    const char* Ar = Ab + (RB) * ABUFB; \
    bf16x8 t0l = *reinterpret_cast<const bf16x8*>(Ar + a0); \
    bf16x8 t0h = *reinterpret_cast<const bf16x8*>(Ar + a0 + 4096); \
    c00 = MFMA32(t0l, __builtin_bit_cast(bf16x8, R##0), c00); \
    c10 = MFMA32(t0h, __builtin_bit_cast(bf16x8, R##0), c10); \
    bf16x8 t1l = *reinterpret_cast<const bf16x8*>(Ar + a1); \
    bf16x8 t1h = *reinterpret_cast<const bf16x8*>(Ar + a1 + 4096); \
    c00 = MFMA32(t1l, __builtin_bit_cast(bf16x8, R##1), c00); \
    c10 = MFMA32(t1h, __builtin_bit_cast(bf16x8, R##1), c10); \
    bf16x8 t2l = *reinterpret_cast<const bf16x8*>(Ar + a2); \
    bf16x8 t2h = *reinterpret_cast<const bf16x8*>(Ar + a2 + 4096); \
    c00 = MFMA32(t2l, __builtin_bit_cast(bf16x8, R##2), c00); \
    c10 = MFMA32(t2h, __builtin_bit_cast(bf16x8, R##2), c10); \
    bf16x8 t3l = *reinterpret_cast<const bf16x8*>(Ar + a3); \
    bf16x8 t3h = *reinterpret_cast<const bf16x8*>(Ar + a3 + 4096); \
    c00 = MFMA32(t3l, __builtin_bit_cast(bf16x8, R##3), c00); \
    c10 = MFMA32(t3h, __builtin_bit_cast(bf16x8, R##3), c10); \
}

#define EPI(ACC, IH) { \
    _Pragma("unroll") \
    for (int reg = 0; reg < 16; ++reg) { \
        int rowD = (reg & 3) + 8 * (reg >> 2) + 4 * lh; \
        Pq[(long)(ibase + (IH) * 32 + rowD) * CBND + w * 32 + l31] = ACC[reg]; \
    } \
}

__global__ __launch_bounds__(1024, 4) void k_conv(const u16* __restrict__ bbn_bf,
                                                  const float* __restrict__ s,
                                                  const float* __restrict__ dinv,
                                                  const u16* __restrict__ g_blk,
                                                  float* __restrict__ P,
                                                  int* __restrict__ flags,
                                                  float* __restrict__ out) {
    __shared__ __align__(16) u16 Alds[2][64 * 64];   // 2 x 8KB supertiles
    __shared__ int s_old;

    int bx = blockIdx.x;
    int jq = bx & 1;                   // j-half; constant per XCD (stride-8 dispatch)
    int it = bx >> 1;                  // 0..127
    int ibase = it * 64;
    int jbase = jq * JQ;

    int tid = threadIdx.x;
    int w = tid >> 6, l = tid & 63;
    int lr = l & 15, lg = l >> 4, l31 = l & 31, lh = l >> 5;
    int iq = w & 3, jq8 = w >> 2;      // gen wave tile: 16i x 16j (4x4 waves)

    // gen hoists
    bf16x8 fragI = *reinterpret_cast<const bf16x8*>(bbn_bf + (ibase + iq * 16 + lr) * BBND + lg * 8);
    float si = s[ibase + iq * 16 + lr];

    char* Ab = (char*)&Alds[0][0];
    float* Pq = P + (long)jq * (NROWS * CBND);

    // B global base: octet (jbase/8 + T*8 + t*2 + lh), c = w*32 + l31
    const char* gB = (const char*)g_blk + (long)jbase * 1024 + lh * 8192
                   + (w * 32 + l31) * 16;

    // A-frag reads: rows l31 (i-lo) / l31+32 (i-hi, +4096B), k-step t slot = 2t+lh,
    // phys = slot ^ (row&7); (l31+32)&7 == l31&7 so i-hi shares the XOR.
    int r7 = l31 & 7;
    int abase = l31 * 128;
    int a0 = abase + (((0 + lh) ^ r7) << 4);
    int a1 = abase + (((2 + lh) ^ r7) << 4);
    int a2 = abase + (((4 + lh) ^ r7) << 4);
    int a3 = abase + (((6 + lh) ^ r7) << 4);

    // gen write: row = iq*16+lr, logical slot = jq8*2 + (lg>>1), byte +(lg&1)*8
    int grow = iq * 16 + lr;
    int gw = grow * 128 + (((jq8 * 2 + (lg >> 1)) ^ (grow & 7)) << 4) + (lg & 1) * 8;

    f32x16 c00 = ZERO16, c10 = ZERO16;

    u32x4 rA0, rA1, rA2, rA3;
    u32x4 rB0, rB1, rB2, rB3;
    bf16x8 gJ;
    f32x4 gS;

    // prologue
    LOADG(0);
    GENP(0);
    LOADG(1);
    LOADB(0, rA);
    BAR;

    for (int st2 = 0; st2 < NR; st2 += 2) {
        LOADB(st2 + 1, rB);
        GENP(1);
        if (st2 + 2 < NR) LOADG(st2 + 2);
        CONVP(0, rA);
        BAR;
        int tn = (st2 + 2 < NR) ? st2 + 2 : NR - 1;   // tail: redundant, never read
        LOADB(tn, rA);
        if (st2 + 2 < NR) {
            GENP(0);
            if (st2 + 3 < NR) LOADG(st2 + 3);
        }
        CONVP(1, rB);
        BAR;
    }

    EPI(c00, 0);
    EPI(c10, 1);

    // ---- split-K combine (second finisher) ----
    __syncthreads();                       // all P stores of this block retired
    __threadfence();                       // device-scope release
    if (tid == 0) s_old = atomicAdd(&flags[it], 1);
    __syncthreads();
    if (s_old == 1) {
        __threadfence();                   // acquire: see partner's P
#pragma unroll
        for (int p = 0; p < 8; ++p) {
            int idx = p * 1024 + tid;      // 8192 f32x4 slots in 64i x 512c tile
            int row = idx >> 7, c4 = idx & 127;
            long off = (long)(ibase + row) * CBND + c4 * 4;
            float di = dinv[ibase + row];
            f32x4 a = *reinterpret_cast<const f32x4*>(P + off);
            f32x4 b = *reinterpret_cast<const f32x4*>(P + (long)NROWS * CBND + off);
            f32x4 v;
#pragma unroll
            for (int e = 0; e < 4; ++e) v[e] = sigmoidf_fast((a[e] + b[e]) * di);
            *reinterpret_cast<f32x4*>(out + off) = v;
        }
    }
}

extern "C" void kernel_launch(void* const* d_in, const int* in_sizes, int n_in,
                              void* d_out, int out_size, void* d_ws, size_t ws_size,
                              hipStream_t stream) {
    const float* bbn = (const float*)d_in[0];   // [8192,32]
    const float* cbn = (const float*)d_in[1];   // [8192,512]
    const float* W   = (const float*)d_in[2];   // [512,512]
    const float* b   = (const float*)d_in[3];   // [512]
    float* out = (float*)d_out;                 // [8192,512] f32

    char* ws = (char*)d_ws;
    float* s      = (float*)ws;  ws += NROWS * 4;
    float* dinv   = (float*)ws;  ws += NROWS * 4;
    u16* bbn_bf   = (u16*)ws;    ws += NROWS * BBND * 2;
    u16* WT       = (u16*)ws;    ws += CBND * CBND * 2;
    u16* g_blk    = (u16*)ws;    ws += (size_t)CBND * NROWS * 2;
    float* P      = (float*)ws;  ws += (size_t)2 * NROWS * CBND * 4;   // 32MB partials
    int* flags    = (int*)ws;    ws += 128 * 4;

    k_prep<<<512, 512, 0, stream>>>(bbn, W, s, bbn_bf, WT, flags);
    k_deg<<<NROWS / 16, 1024, 0, stream>>>(bbn_bf, s, dinv);
    k_fc<<<(NROWS / 64) * 2, 512, 0, stream>>>(cbn, WT, b, dinv, g_blk);
    k_conv<<<(NROWS / 64) * 2, 1024, 0, stream>>>(bbn_bf, s, dinv, g_blk, P, flags, out);
}

// Round 21
// 146.282 us; speedup vs baseline: 1.9866x; 1.9866x over previous
//
#include <hip/hip_runtime.h>

#define NROWS 8192
#define BBND  32
#define CBND  512
#define JQ    4096            // j-range per block (2 halves)
#define NR    64              // rounds of 64j per block
#define ABUFB 8192            // A LDS buffer bytes (64 rows x 128B)

typedef unsigned short u16;
typedef unsigned int   u32;
typedef __bf16 bf16x8 __attribute__((ext_vector_type(8)));
typedef float  f32x4  __attribute__((ext_vector_type(4)));
typedef float  f32x16 __attribute__((ext_vector_type(16)));
typedef u32    u32x4  __attribute__((ext_vector_type(4)));
typedef u32    u32x2  __attribute__((ext_vector_type(2)));

#define ZERO4  (f32x4){0.f,0.f,0.f,0.f}
#define ZERO16 (f32x16){0.f,0.f,0.f,0.f,0.f,0.f,0.f,0.f,0.f,0.f,0.f,0.f,0.f,0.f,0.f,0.f}

// raw barrier: drain LDS ops, keep global loads in flight (no vmcnt drain)
#define BAR asm volatile("s_waitcnt lgkmcnt(0)\n\ts_barrier" ::: "memory")

static __device__ inline u16 f2bf(float f) {
    unsigned u = __builtin_bit_cast(unsigned, f);
    unsigned r = (u + 0x7FFFu + ((u >> 16) & 1u)) >> 16;
    return (u16)r;
}

static __device__ inline float pow14(float base) {
    return __builtin_amdgcn_exp2f(1.4f * __builtin_amdgcn_logf(base));
}

static __device__ inline float adj_eval(float dot, float sij) {
    float x = fabsf(2.f * dot - sij);
    float base = fmaxf(1.f - x * (1.f / 32.f), 0.f);
    return pow14(base);
}

static __device__ inline float sigmoidf_fast(float v) {
    float e = __builtin_amdgcn_exp2f(-1.44269504f * v);
    return 1.f / (1.f + e);
}

static __device__ inline u32 cvtpk(float a, float b) {
    u32 r;
    asm("v_cvt_pk_bf16_f32 %0, %1, %2" : "=v"(r) : "v"(a), "v"(b));
    return r;
}

static __device__ inline f32x4 MFMA16(bf16x8 a, bf16x8 b, f32x4 c) {
    return __builtin_amdgcn_mfma_f32_16x16x32_bf16(a, b, c, 0, 0, 0);
}
static __device__ inline f32x16 MFMA32(bf16x8 a, bf16x8 b, f32x16 c) {
    return __builtin_amdgcn_mfma_f32_32x32x16_bf16(a, b, c, 0, 0, 0);
}

// ---------------- prep: WT transpose + row sums/bf16 (merged, fence-free) ----------------
__global__ __launch_bounds__(512) void k_prep(const float* __restrict__ bbn,
                                              const float* __restrict__ W,
                                              float* __restrict__ s,
                                              u16* __restrict__ bbn_bf,
                                              u16* __restrict__ WT) {
    int idx = blockIdx.x * 512 + threadIdx.x;   // 512 blocks x 512 thr = 262144
    int c = idx >> 9, k = idx & 511;
    WT[idx] = f2bf(W[k * CBND + c]);            // WT[c][k]
    if (idx < NROWS) {
        const f32x4* row = reinterpret_cast<const f32x4*>(bbn + idx * BBND);
        float sum = 0.f;
        u16* dst = bbn_bf + idx * BBND;
#pragma unroll
        for (int q = 0; q < 8; ++q) {
            f32x4 v = row[q];
#pragma unroll
            for (int e = 0; e < 4; ++e) {
                sum += v[e];
                dst[q * 4 + e] = f2bf(v[e]);
            }
        }
        s[idx] = sum;
    }
}

// ---------------- degree: d_i = sum_j adj_ij ; dinv = rsqrt(d+eps) (r18 verbatim) ----------------
__global__ __launch_bounds__(1024) void k_deg(const u16* __restrict__ bbn_bf,
                                              const float* __restrict__ s,
                                              float* __restrict__ dinv) {
    __shared__ float part[16][16];
    int ibase = blockIdx.x * 16;
    int tid = threadIdx.x;
    int w = tid >> 6, l = tid & 63, lg = l >> 4, lr = l & 15;

    bf16x8 afrag = *reinterpret_cast<const bf16x8*>(bbn_bf + (ibase + lr) * BBND + lg * 8);
    float si[4];
#pragma unroll
    for (int r = 0; r < 4; ++r) si[r] = s[ibase + lg * 4 + r];

    float dacc[4] = {0.f, 0.f, 0.f, 0.f};
    int j0 = w * (NROWS / 16);
    bf16x8 nbf = *reinterpret_cast<const bf16x8*>(bbn_bf + (j0 + lr) * BBND + lg * 8);
    float nsj = s[j0 + lr];
    for (int jt = 0; jt < NROWS / 16; jt += 16) {
        bf16x8 bfrag = nbf;
        float sj = nsj;
        if (jt + 16 < NROWS / 16) {
            int jn = j0 + jt + 16;
            nbf = *reinterpret_cast<const bf16x8*>(bbn_bf + (jn + lr) * BBND + lg * 8);
            nsj = s[jn + lr];
        }
        f32x4 dot = MFMA16(afrag, bfrag, ZERO4);
#pragma unroll
        for (int r = 0; r < 4; ++r) dacc[r] += adj_eval(dot[r], si[r] + sj);
    }
#pragma unroll
    for (int off = 1; off < 16; off <<= 1)
#pragma unroll
        for (int r = 0; r < 4; ++r) dacc[r] += __shfl_xor(dacc[r], off, 64);

    if (lr == 0) {
#pragma unroll
        for (int r = 0; r < 4; ++r) part[w][lg * 4 + r] = dacc[r];
    }
    __syncthreads();
    if (tid < 16) {
        float d = 0.f;
#pragma unroll
        for (int q = 0; q < 16; ++q) d += part[q][tid];
        dinv[ibase + tid] = rsqrtf(d + 1e-8f);
    }
}

// ---------------- fc: g_blk[(j>>3)*512 + c][j&7] = dinv_j * (cbn@W + b)[j][c] (r18 verbatim) ----------------
__global__ __launch_bounds__(512) void k_fc(const float* __restrict__ cbn,
                                            const u16* __restrict__ WT,
                                            const float* __restrict__ bvec,
                                            const float* __restrict__ dinv,
                                            u16* __restrict__ g_blk) {
    __shared__ __align__(16) u16 Clds[64 * 512];   // 64 j-rows x 512 k (bf16)
    int bx = blockIdx.x;
    int ch = bx & 1;
    int jcol = (bx >> 1) * 64;
    int tid = threadIdx.x;
    int w = tid >> 6, l = tid & 63, lg = l >> 4, lr = l & 15;
    int wq = w & 3, jh = w >> 2;

    char* Cl = (char*)&Clds[0];

#pragma unroll
    for (int p = 0; p < 8; ++p) {
        int gidx = p * 512 + tid;
        int row = gidx >> 6, sl = gidx & 63;
        const f32x4* src = reinterpret_cast<const f32x4*>(cbn + (jcol + row) * CBND + sl * 8);
        f32x4 v0 = src[0], v1 = src[1];
        bf16x8 bv;
#pragma unroll
        for (int e = 0; e < 4; ++e) { bv[e] = (__bf16)v0[e]; bv[e + 4] = (__bf16)v1[e]; }
        *reinterpret_cast<bf16x8*>(Cl + row * 1024 + ((sl ^ (row & 7)) << 4)) = bv;
    }
    __syncthreads();

    int r7 = lr & 7;
    for (int q = 0; q < 4; ++q) {
        int cb = ch * 4 + q;
        int crow = cb * 64 + wq * 16;
        f32x4 acc0 = ZERO4, acc1 = ZERO4;
        for (int k0 = 0; k0 < CBND; k0 += 32) {
            bf16x8 afrag = *reinterpret_cast<const bf16x8*>(WT + (crow + lr) * CBND + k0 + lg * 8);
            int slot = (k0 >> 3) + lg;
            int row0 = jh * 32 + lr;
            bf16x8 b0 = *reinterpret_cast<const bf16x8*>(Cl + row0 * 1024 + ((slot ^ r7) << 4));
            bf16x8 b1 = *reinterpret_cast<const bf16x8*>(Cl + (row0 + 16) * 1024 + ((slot ^ r7) << 4));
            acc0 = MFMA16(afrag, b0, acc0);
            acc1 = MFMA16(afrag, b1, acc1);
        }
#pragma unroll
        for (int f = 0; f < 2; ++f) {
            f32x4 af = f ? acc1 : acc0;
#pragma unroll
            for (int r = 0; r < 4; ++r) {
                int c = crow + lg * 4 + r;
                int j = jcol + jh * 32 + f * 16 + lr;
                float val = af[r] + bvec[c];
                g_blk[(((j >> 3) * 512 + c) << 3) + (j & 7)] = f2bf(val * dinv[j]);
            }
        }
    }
}

// ---------------- conv: partial sums P[jh] (r18 verbatim, 86.7us proven) ----------------
#define LOADB(T, R) { \
    const char* p = gB + (long)(T) * 65536; \
    R##0 = *reinterpret_cast<const u32x4*>(p); \
    R##1 = *reinterpret_cast<const u32x4*>(p + 16384); \
    R##2 = *reinterpret_cast<const u32x4*>(p + 32768); \
    R##3 = *reinterpret_cast<const u32x4*>(p + 49152); \
}

#define LOADG(ST) { \
    int jg = jbase + (ST) * 64 + jq8 * 16; \
    gJ = *reinterpret_cast<const bf16x8*>(bbn_bf + (jg + lr) * BBND + lg * 8); \
    gS = *reinterpret_cast<const f32x4*>(s + jg + lg * 4); \
}

#define GENP(WB) { \
    f32x4 dot = MFMA16(gJ, fragI, ZERO4); \
    u32 p0 = cvtpk(adj_eval(dot[0], si + gS[0]), adj_eval(dot[1], si + gS[1])); \
    u32 p1 = cvtpk(adj_eval(dot[2], si + gS[2]), adj_eval(dot[3], si + gS[3])); \
    *reinterpret_cast<u32x2*>(Ab + (WB) * ABUFB + gw) = (u32x2){p0, p1}; \
}

#define CONVP(RB, R) { \
    const char* Ar = Ab + (RB) * ABUFB; \
    bf16x8 t0l = *reinterpret_cast<const bf16x8*>(Ar + a0); \
    bf16x8 t0h = *reinterpret_cast<const bf16x8*>(Ar + a0 + 4096); \
    c00 = MFMA32(t0l, __builtin_bit_cast(bf16x8, R##0), c00); \
    c10 = MFMA32(t0h, __builtin_bit_cast(bf16x8, R##0), c10); \
    bf16x8 t1l = *reinterpret_cast<const bf16x8*>(Ar + a1); \
    bf16x8 t1h = *reinterpret_cast<const bf16x8*>(Ar + a1 + 4096); \
    c00 = MFMA32(t1l, __builtin_bit_cast(bf16x8, R##1), c00); \
    c10 = MFMA32(t1h, __builtin_bit_cast(bf16x8, R##1), c10); \
    bf16x8 t2l = *reinterpret_cast<const bf16x8*>(Ar + a2); \
    bf16x8 t2h = *reinterpret_cast<const bf16x8*>(Ar + a2 + 4096); \
    c00 = MFMA32(t2l, __builtin_bit_cast(bf16x8, R##2), c00); \
    c10 = MFMA32(t2h, __builtin_bit_cast(bf16x8, R##2), c10); \
    bf16x8 t3l = *reinterpret_cast<const bf16x8*>(Ar + a3); \
    bf16x8 t3h = *reinterpret_cast<const bf16x8*>(Ar + a3 + 4096); \
    c00 = MFMA32(t3l, __builtin_bit_cast(bf16x8, R##3), c00); \
    c10 = MFMA32(t3h, __builtin_bit_cast(bf16x8, R##3), c10); \
}

#define EPI(ACC, IH) { \
    _Pragma("unroll") \
    for (int reg = 0; reg < 16; ++reg) { \
        int rowD = (reg & 3) + 8 * (reg >> 2) + 4 * lh; \
        Pq[(long)(ibase + (IH) * 32 + rowD) * CBND + w * 32 + l31] = ACC[reg]; \
    } \
}

__global__ __launch_bounds__(1024, 4) void k_conv(const u16* __restrict__ bbn_bf,
                                                  const float* __restrict__ s,
                                                  const u16* __restrict__ g_blk,
                                                  float* __restrict__ P) {
    __shared__ __align__(16) u16 Alds[2][64 * 64];   // 2 x 8KB supertiles

    int bx = blockIdx.x;
    int jq = bx & 1;                   // j-half; constant per XCD (stride-8 dispatch)
    int it = bx >> 1;                  // 0..127
    int ibase = it * 64;
    int jbase = jq * JQ;

    int tid = threadIdx.x;
    int w = tid >> 6, l = tid & 63;
    int lr = l & 15, lg = l >> 4, l31 = l & 31, lh = l >> 5;
    int iq = w & 3, jq8 = w >> 2;      // gen wave tile: 16i x 16j (4x4 waves)

    // gen hoists
    bf16x8 fragI = *reinterpret_cast<const bf16x8*>(bbn_bf + (ibase + iq * 16 + lr) * BBND + lg * 8);
    float si = s[ibase + iq * 16 + lr];

    char* Ab = (char*)&Alds[0][0];
    float* Pq = P + (long)jq * (NROWS * CBND);

    // B global base: octet (jbase/8 + T*8 + t*2 + lh), c = w*32 + l31
    const char* gB = (const char*)g_blk + (long)jbase * 1024 + lh * 8192
                   + (w * 32 + l31) * 16;

    // A-frag reads: rows l31 (i-lo) / l31+32 (i-hi, +4096B), k-step t slot = 2t+lh,
    // phys = slot ^ (row&7); (l31+32)&7 == l31&7 so i-hi shares the XOR.
    int r7 = l31 & 7;
    int abase = l31 * 128;
    int a0 = abase + (((0 + lh) ^ r7) << 4);
    int a1 = abase + (((2 + lh) ^ r7) << 4);
    int a2 = abase + (((4 + lh) ^ r7) << 4);
    int a3 = abase + (((6 + lh) ^ r7) << 4);

    // gen write: row = iq*16+lr, logical slot = jq8*2 + (lg>>1), byte +(lg&1)*8
    int grow = iq * 16 + lr;
    int gw = grow * 128 + (((jq8 * 2 + (lg >> 1)) ^ (grow & 7)) << 4) + (lg & 1) * 8;

    f32x16 c00 = ZERO16, c10 = ZERO16;

    u32x4 rA0, rA1, rA2, rA3;
    u32x4 rB0, rB1, rB2, rB3;
    bf16x8 gJ;
    f32x4 gS;

    // prologue
    LOADG(0);
    GENP(0);
    LOADG(1);
    LOADB(0, rA);
    BAR;

    for (int st2 = 0; st2 < NR; st2 += 2) {
        LOADB(st2 + 1, rB);
        GENP(1);
        if (st2 + 2 < NR) LOADG(st2 + 2);
        CONVP(0, rA);
        BAR;
        int tn = (st2 + 2 < NR) ? st2 + 2 : NR - 1;   // tail: redundant, never read
        LOADB(tn, rA);
        if (st2 + 2 < NR) {
            GENP(0);
            if (st2 + 3 < NR) LOADG(st2 + 3);
        }
        CONVP(1, rB);
        BAR;
    }

    EPI(c00, 0);
    EPI(c10, 1);
}

// ---------------- combine: out = sigmoid(dinv_i * (P0 + P1)) (r18 verbatim) ----------------
__global__ __launch_bounds__(256) void k_comb(const float* __restrict__ dinv,
                                              const float* __restrict__ P,
                                              float* __restrict__ out) {
    int idx = blockIdx.x * 256 + threadIdx.x;   // f32x4 index; 1,048,576 total
    float di = dinv[idx >> 7];
    f32x4 a = *reinterpret_cast<const f32x4*>(P + (long)idx * 4);
    f32x4 b = *reinterpret_cast<const f32x4*>(P + (long)NROWS * CBND + (long)idx * 4);
    f32x4 v;
#pragma unroll
    for (int e = 0; e < 4; ++e) v[e] = sigmoidf_fast((a[e] + b[e]) * di);
    *reinterpret_cast<f32x4*>(out + (long)idx * 4) = v;
}

extern "C" void kernel_launch(void* const* d_in, const int* in_sizes, int n_in,
                              void* d_out, int out_size, void* d_ws, size_t ws_size,
                              hipStream_t stream) {
    const float* bbn = (const float*)d_in[0];   // [8192,32]
    const float* cbn = (const float*)d_in[1];   // [8192,512]
    const float* W   = (const float*)d_in[2];   // [512,512]
    const float* b   = (const float*)d_in[3];   // [512]
    float* out = (float*)d_out;                 // [8192,512] f32

    char* ws = (char*)d_ws;
    float* s      = (float*)ws;  ws += NROWS * 4;
    float* dinv   = (float*)ws;  ws += NROWS * 4;
    u16* bbn_bf   = (u16*)ws;    ws += NROWS * BBND * 2;
    u16* WT       = (u16*)ws;    ws += CBND * CBND * 2;
    u16* g_blk    = (u16*)ws;    ws += (size_t)CBND * NROWS * 2;
    float* P      = (float*)ws;  ws += (size_t)2 * NROWS * CBND * 4;   // 32MB partials

    k_prep<<<512, 512, 0, stream>>>(bbn, W, s, bbn_bf, WT);
    k_deg<<<NROWS / 16, 1024, 0, stream>>>(bbn_bf, s, dinv);
    k_fc<<<(NROWS / 64) * 2, 512, 0, stream>>>(cbn, WT, b, dinv, g_blk);
    k_conv<<<(NROWS / 64) * 2, 1024, 0, stream>>>(bbn_bf, s, g_blk, P);
    k_comb<<<(NROWS * CBND / 4) / 256, 256, 0, stream>>>(dinv, P, out);
}

// Round 22
// 140.439 us; speedup vs baseline: 2.0692x; 1.0416x over previous
//
#include <hip/hip_runtime.h>

#define NROWS 8192
#define BBND  32
#define CBND  512
#define JQ    4096            // j-range per block (2 halves)
#define NR    64              // rounds of 64j per block
#define ABUFB 8192            // A LDS buffer bytes (64 rows x 128B)

typedef unsigned short u16;
typedef unsigned int   u32;
typedef __bf16 bf16x8 __attribute__((ext_vector_type(8)));
typedef float  f32x4  __attribute__((ext_vector_type(4)));
typedef float  f32x16 __attribute__((ext_vector_type(16)));
typedef u32    u32x4  __attribute__((ext_vector_type(4)));
typedef u32    u32x2  __attribute__((ext_vector_type(2)));

#define ZERO4  (f32x4){0.f,0.f,0.f,0.f}
#define ZERO16 (f32x16){0.f,0.f,0.f,0.f,0.f,0.f,0.f,0.f,0.f,0.f,0.f,0.f,0.f,0.f,0.f,0.f}

// raw barrier: drain LDS ops, keep global loads in flight (no vmcnt drain)
#define BAR asm volatile("s_waitcnt lgkmcnt(0)\n\ts_barrier" ::: "memory")

static __device__ inline u16 f2bf(float f) {
    unsigned u = __builtin_bit_cast(unsigned, f);
    unsigned r = (u + 0x7FFFu + ((u >> 16) & 1u)) >> 16;
    return (u16)r;
}

static __device__ inline float pow14(float base) {
    return __builtin_amdgcn_exp2f(1.4f * __builtin_amdgcn_logf(base));
}

static __device__ inline float adj_eval(float dot, float sij) {
    float x = fabsf(2.f * dot - sij);
    float base = fmaxf(1.f - x * (1.f / 32.f), 0.f);
    return pow14(base);
}

static __device__ inline float sigmoidf_fast(float v) {
    float e = __builtin_amdgcn_exp2f(-1.44269504f * v);
    return 1.f / (1.f + e);
}

static __device__ inline u32 cvtpk(float a, float b) {
    u32 r;
    asm("v_cvt_pk_bf16_f32 %0, %1, %2" : "=v"(r) : "v"(a), "v"(b));
    return r;
}

static __device__ inline f32x4 MFMA16(bf16x8 a, bf16x8 b, f32x4 c) {
    return __builtin_amdgcn_mfma_f32_16x16x32_bf16(a, b, c, 0, 0, 0);
}
static __device__ inline f32x16 MFMA32(bf16x8 a, bf16x8 b, f32x16 c) {
    return __builtin_amdgcn_mfma_f32_32x32x16_bf16(a, b, c, 0, 0, 0);
}

// ---------------- prep: WT transpose + row sums/bf16 (merged, fence-free) ----------------
__global__ __launch_bounds__(512) void k_prep(const float* __restrict__ bbn,
                                              const float* __restrict__ W,
                                              float* __restrict__ s,
                                              u16* __restrict__ bbn_bf,
                                              u16* __restrict__ WT) {
    int idx = blockIdx.x * 512 + threadIdx.x;   // 512 blocks x 512 thr = 262144
    int c = idx >> 9, k = idx & 511;
    WT[idx] = f2bf(W[k * CBND + c]);            // WT[c][k]
    if (idx < NROWS) {
        const f32x4* row = reinterpret_cast<const f32x4*>(bbn + idx * BBND);
        float sum = 0.f;
        u16* dst = bbn_bf + idx * BBND;
#pragma unroll
        for (int q = 0; q < 8; ++q) {
            f32x4 v = row[q];
#pragma unroll
            for (int e = 0; e < 4; ++e) {
                sum += v[e];
                dst[q * 4 + e] = f2bf(v[e]);
            }
        }
        s[idx] = sum;
    }
}

// ---------------- fused deg + fc (independent: fc no longer needs dinv) ----------------
// Grid 768 x 1024 thr: blocks 0..511 = degree (r21-verbatim math), blocks
// 512..767 = fc WITHOUT the dinv_j factor (moved into conv's adj-gen), using
// r19's value-verified 1024-thr mapping. deg is VALU/trans-bound, fc is
// MFMA/LDS-bound -> they overlap on the CUs; saves one launch + gap.
__global__ __launch_bounds__(1024, 4) void k_degfc(const u16* __restrict__ bbn_bf,
                                                   const float* __restrict__ s,
                                                   float* __restrict__ dinv,
                                                   const float* __restrict__ cbn,
                                                   const u16* __restrict__ WT,
                                                   const float* __restrict__ bvec,
                                                   u16* __restrict__ g_blk) {
    __shared__ __align__(16) u16 Clds[64 * 512];   // fc: 64KB tile; deg: aliases 1KB
    int bx = blockIdx.x;
    int tid = threadIdx.x;
    int w = tid >> 6, l = tid & 63, lg = l >> 4, lr = l & 15;

    if (bx < 512) {
        // ---- degree: d_i = sum_j adj_ij ; dinv = rsqrt(d+eps) ----
        float (*part)[16] = reinterpret_cast<float(*)[16]>(&Clds[0]);
        int ibase = bx * 16;

        bf16x8 afrag = *reinterpret_cast<const bf16x8*>(bbn_bf + (ibase + lr) * BBND + lg * 8);
        float si[4];
#pragma unroll
        for (int r = 0; r < 4; ++r) si[r] = s[ibase + lg * 4 + r];

        float dacc[4] = {0.f, 0.f, 0.f, 0.f};
        int j0 = w * (NROWS / 16);
        bf16x8 nbf = *reinterpret_cast<const bf16x8*>(bbn_bf + (j0 + lr) * BBND + lg * 8);
        float nsj = s[j0 + lr];
        for (int jt = 0; jt < NROWS / 16; jt += 16) {
            bf16x8 bfrag = nbf;
            float sj = nsj;
            if (jt + 16 < NROWS / 16) {
                int jn = j0 + jt + 16;
                nbf = *reinterpret_cast<const bf16x8*>(bbn_bf + (jn + lr) * BBND + lg * 8);
                nsj = s[jn + lr];
            }
            f32x4 dot = MFMA16(afrag, bfrag, ZERO4);
#pragma unroll
            for (int r = 0; r < 4; ++r) dacc[r] += adj_eval(dot[r], si[r] + sj);
        }
#pragma unroll
        for (int off = 1; off < 16; off <<= 1)
#pragma unroll
            for (int r = 0; r < 4; ++r) dacc[r] += __shfl_xor(dacc[r], off, 64);

        if (lr == 0) {
#pragma unroll
            for (int r = 0; r < 4; ++r) part[w][lg * 4 + r] = dacc[r];
        }
        __syncthreads();
        if (tid < 16) {
            float d = 0.f;
#pragma unroll
            for (int q = 0; q < 16; ++q) d += part[q][tid];
            dinv[ibase + tid] = rsqrtf(d + 1e-8f);
        }
    } else {
        // ---- fc: g_blk[(j>>3)*512 + c][j&7] = (cbn@W + b)[j][c] (NO dinv) ----
        char* Cl = (char*)&Clds[0];
        int fb = bx - 512;                 // 0..255
        int ch = fb & 1;
        int jcol = (fb >> 1) * 64;

#pragma unroll
        for (int p = 0; p < 4; ++p) {
            int gidx = p * 1024 + tid;     // 4096 16B-slots of the 64x512 tile
            int row = gidx >> 6, sl = gidx & 63;
            const f32x4* src = reinterpret_cast<const f32x4*>(cbn + (jcol + row) * CBND + sl * 8);
            f32x4 v0 = src[0], v1 = src[1];
            bf16x8 bv;
#pragma unroll
            for (int e = 0; e < 4; ++e) { bv[e] = (__bf16)v0[e]; bv[e + 4] = (__bf16)v1[e]; }
            *reinterpret_cast<bf16x8*>(Cl + row * 1024 + ((sl ^ (row & 7)) << 4)) = bv;
        }
        __syncthreads();

        int wq = w & 3, jh = (w >> 2) & 1, qh = w >> 3;
        int r7 = lr & 7;
#pragma unroll
        for (int qq = 0; qq < 2; ++qq) {
            int cb = ch * 4 + qh * 2 + qq;
            int crow = cb * 64 + wq * 16;
            f32x4 acc0 = ZERO4, acc1 = ZERO4;
            for (int k0 = 0; k0 < CBND; k0 += 32) {
                bf16x8 afrag = *reinterpret_cast<const bf16x8*>(WT + (crow + lr) * CBND + k0 + lg * 8);
                int slot = (k0 >> 3) + lg;
                int row0 = jh * 32 + lr;
                bf16x8 b0 = *reinterpret_cast<const bf16x8*>(Cl + row0 * 1024 + ((slot ^ r7) << 4));
                bf16x8 b1 = *reinterpret_cast<const bf16x8*>(Cl + (row0 + 16) * 1024 + ((slot ^ r7) << 4));
                acc0 = MFMA16(afrag, b0, acc0);
                acc1 = MFMA16(afrag, b1, acc1);
            }
#pragma unroll
            for (int f = 0; f < 2; ++f) {
                f32x4 af = f ? acc1 : acc0;
#pragma unroll
                for (int r = 0; r < 4; ++r) {
                    int c = crow + lg * 4 + r;
                    int j = jcol + jh * 32 + f * 16 + lr;
                    g_blk[(((j >> 3) * 512 + c) << 3) + (j & 7)] = f2bf(af[r] + bvec[c]);
                }
            }
        }
    }
}

// ---------------- conv: partial sums P[jh] = sum_j (adj_ij*dinv_j) * g'[:,j] ----------------
// r18/r21 conv core with the dinv_j factor folded into adj-gen (4 mults + one
// f32x4 load per GEN). Same MFMA chains, same layouts.

#define LOADB(T, R) { \
    const char* p = gB + (long)(T) * 65536; \
    R##0 = *reinterpret_cast<const u32x4*>(p); \
    R##1 = *reinterpret_cast<const u32x4*>(p + 16384); \
    R##2 = *reinterpret_cast<const u32x4*>(p + 32768); \
    R##3 = *reinterpret_cast<const u32x4*>(p + 49152); \
}

#define LOADG(ST) { \
    int jg = jbase + (ST) * 64 + jq8 * 16; \
    gJ = *reinterpret_cast<const bf16x8*>(bbn_bf + (jg + lr) * BBND + lg * 8); \
    gS = *reinterpret_cast<const f32x4*>(s + jg + lg * 4); \
    gD = *reinterpret_cast<const f32x4*>(dinv + jg + lg * 4); \
}

#define GENP(WB) { \
    f32x4 dot = MFMA16(gJ, fragI, ZERO4); \
    u32 p0 = cvtpk(adj_eval(dot[0], si + gS[0]) * gD[0], adj_eval(dot[1], si + gS[1]) * gD[1]); \
    u32 p1 = cvtpk(adj_eval(dot[2], si + gS[2]) * gD[2], adj_eval(dot[3], si + gS[3]) * gD[3]); \
    *reinterpret_cast<u32x2*>(Ab + (WB) * ABUFB + gw) = (u32x2){p0, p1}; \
}

#define CONVP(RB, R) { \
    const char* Ar = Ab + (RB) * ABUFB; \
    bf16x8 t0l = *reinterpret_cast<const bf16x8*>(Ar + a0); \
    bf16x8 t0h = *reinterpret_cast<const bf16x8*>(Ar + a0 + 4096); \
    c00 = MFMA32(t0l, __builtin_bit_cast(bf16x8, R##0), c00); \
    c10 = MFMA32(t0h, __builtin_bit_cast(bf16x8, R##0), c10); \
    bf16x8 t1l = *reinterpret_cast<const bf16x8*>(Ar + a1); \
    bf16x8 t1h = *reinterpret_cast<const bf16x8*>(Ar + a1 + 4096); \
    c00 = MFMA32(t1l, __builtin_bit_cast(bf16x8, R##1), c00); \
    c10 = MFMA32(t1h, __builtin_bit_cast(bf16x8, R##1), c10); \
    bf16x8 t2l = *reinterpret_cast<const bf16x8*>(Ar + a2); \
    bf16x8 t2h = *reinterpret_cast<const bf16x8*>(Ar + a2 + 4096); \
    c00 = MFMA32(t2l, __builtin_bit_cast(bf16x8, R##2), c00); \
    c10 = MFMA32(t2h, __builtin_bit_cast(bf16x8, R##2), c10); \
    bf16x8 t3l = *reinterpret_cast<const bf16x8*>(Ar + a3); \
    bf16x8 t3h = *reinterpret_cast<const bf16x8*>(Ar + a3 + 4096); \
    c00 = MFMA32(t3l, __builtin_bit_cast(bf16x8, R##3), c00); \
    c10 = MFMA32(t3h, __builtin_bit_cast(bf16x8, R##3), c10); \
}

#define EPI(ACC, IH) { \
    _Pragma("unroll") \
    for (int reg = 0; reg < 16; ++reg) { \
        int rowD = (reg & 3) + 8 * (reg >> 2) + 4 * lh; \
        Pq[(long)(ibase + (IH) * 32 + rowD) * CBND + w * 32 + l31] = ACC[reg]; \
    } \
}

__global__ __launch_bounds__(1024, 4) void k_conv(const u16* __restrict__ bbn_bf,
                                                  const float* __restrict__ s,
                                                  const float* __restrict__ dinv,
                                                  const u16* __restrict__ g_blk,
                                                  float* __restrict__ P) {
    __shared__ __align__(16) u16 Alds[2][64 * 64];   // 2 x 8KB supertiles

    int bx = blockIdx.x;
    int jq = bx & 1;                   // j-half; constant per XCD (stride-8 dispatch)
    int it = bx >> 1;                  // 0..127
    int ibase = it * 64;
    int jbase = jq * JQ;

    int tid = threadIdx.x;
    int w = tid >> 6, l = tid & 63;
    int lr = l & 15, lg = l >> 4, l31 = l & 31, lh = l >> 5;
    int iq = w & 3, jq8 = w >> 2;      // gen wave tile: 16i x 16j (4x4 waves)

    // gen hoists
    bf16x8 fragI = *reinterpret_cast<const bf16x8*>(bbn_bf + (ibase + iq * 16 + lr) * BBND + lg * 8);
    float si = s[ibase + iq * 16 + lr];

    char* Ab = (char*)&Alds[0][0];
    float* Pq = P + (long)jq * (NROWS * CBND);

    // B global base: octet (jbase/8 + T*8 + t*2 + lh), c = w*32 + l31
    const char* gB = (const char*)g_blk + (long)jbase * 1024 + lh * 8192
                   + (w * 32 + l31) * 16;

    // A-frag reads: rows l31 (i-lo) / l31+32 (i-hi, +4096B), k-step t slot = 2t+lh,
    // phys = slot ^ (row&7); (l31+32)&7 == l31&7 so i-hi shares the XOR.
    int r7 = l31 & 7;
    int abase = l31 * 128;
    int a0 = abase + (((0 + lh) ^ r7) << 4);
    int a1 = abase + (((2 + lh) ^ r7) << 4);
    int a2 = abase + (((4 + lh) ^ r7) << 4);
    int a3 = abase + (((6 + lh) ^ r7) << 4);

    // gen write: row = iq*16+lr, logical slot = jq8*2 + (lg>>1), byte +(lg&1)*8
    int grow = iq * 16 + lr;
    int gw = grow * 128 + (((jq8 * 2 + (lg >> 1)) ^ (grow & 7)) << 4) + (lg & 1) * 8;

    f32x16 c00 = ZERO16, c10 = ZERO16;

    u32x4 rA0, rA1, rA2, rA3;
    u32x4 rB0, rB1, rB2, rB3;
    bf16x8 gJ;
    f32x4 gS, gD;

    // prologue
    LOADG(0);
    GENP(0);
    LOADG(1);
    LOADB(0, rA);
    BAR;

    for (int st2 = 0; st2 < NR; st2 += 2) {
        LOADB(st2 + 1, rB);
        GENP(1);
        if (st2 + 2 < NR) LOADG(st2 + 2);
        CONVP(0, rA);
        BAR;
        int tn = (st2 + 2 < NR) ? st2 + 2 : NR - 1;   // tail: redundant, never read
        LOADB(tn, rA);
        if (st2 + 2 < NR) {
            GENP(0);
            if (st2 + 3 < NR) LOADG(st2 + 3);
        }
        CONVP(1, rB);
        BAR;
    }

    EPI(c00, 0);
    EPI(c10, 1);
}

// ---------------- combine: out = sigmoid(dinv_i * (P0 + P1)) ----------------
__global__ __launch_bounds__(256) void k_comb(const float* __restrict__ dinv,
                                              const float* __restrict__ P,
                                              float* __restrict__ out) {
    int idx = blockIdx.x * 256 + threadIdx.x;   // f32x4 index; 1,048,576 total
    float di = dinv[idx >> 7];
    f32x4 a = *reinterpret_cast<const f32x4*>(P + (long)idx * 4);
    f32x4 b = *reinterpret_cast<const f32x4*>(P + (long)NROWS * CBND + (long)idx * 4);
    f32x4 v;
#pragma unroll
    for (int e = 0; e < 4; ++e) v[e] = sigmoidf_fast((a[e] + b[e]) * di);
    *reinterpret_cast<f32x4*>(out + (long)idx * 4) = v;
}

extern "C" void kernel_launch(void* const* d_in, const int* in_sizes, int n_in,
                              void* d_out, int out_size, void* d_ws, size_t ws_size,
                              hipStream_t stream) {
    const float* bbn = (const float*)d_in[0];   // [8192,32]
    const float* cbn = (const float*)d_in[1];   // [8192,512]
    const float* W   = (const float*)d_in[2];   // [512,512]
    const float* b   = (const float*)d_in[3];   // [512]
    float* out = (float*)d_out;                 // [8192,512] f32

    char* ws = (char*)d_ws;
    float* s      = (float*)ws;  ws += NROWS * 4;
    float* dinv   = (float*)ws;  ws += NROWS * 4;
    u16* bbn_bf   = (u16*)ws;    ws += NROWS * BBND * 2;
    u16* WT       = (u16*)ws;    ws += CBND * CBND * 2;
    u16* g_blk    = (u16*)ws;    ws += (size_t)CBND * NROWS * 2;
    float* P      = (float*)ws;  ws += (size_t)2 * NROWS * CBND * 4;   // 32MB partials

    k_prep<<<512, 512, 0, stream>>>(bbn, W, s, bbn_bf, WT);
    k_degfc<<<768, 1024, 0, stream>>>(bbn_bf, s, dinv, cbn, WT, b, g_blk);
    k_conv<<<(NROWS / 64) * 2, 1024, 0, stream>>>(bbn_bf, s, dinv, g_blk, P);
    k_comb<<<(NROWS * CBND / 4) / 256, 256, 0, stream>>>(dinv, P, out);
}